// Round 3
// baseline (269.654 us; speedup 1.0000x reference)
//
#include <hip/hip_runtime.h>
#include <hip/hip_fp16.h>

#define BB 4
#define CC 3
#define HH 384
#define WW 384
#define FF 5
#define KK 25            // FF*FF
#define HW (HH*WW)
#define WP 192           // 16B pair-entries per row
#define TOT (BB*HH*WP)   // entries per table copy

#define TX 64            // tile width (pixels) — 32 lanes x 2 px
#define TY 2             // tile height — block = 1 wave (64 threads)

typedef float fx2 __attribute__((ext_vector_type(2)));

__device__ __forceinline__ fx2 nt_load2(const float* p) {
    return __builtin_nontemporal_load((const fx2*)p);
}

// pack one pixel (3 fp32 channels) -> 8B: x = h(c0)|h(c1)<<16, y = h(c2)
__device__ __forceinline__ uint2 pack_px(float c0, float c1, float c2) {
    __half2 h01 = __floats2half2_rn(c0, c1);
    uint2 r;
    r.x = *(const unsigned int*)&h01;
    r.y = (unsigned int)__half_as_ushort(__float2half_rn(c2));
    return r;
}

// Dual fp16 pixel-pair tables: copy A entry j = pixels (2j,2j+1);
// copy B entry j = (2j+1, 2j+2 clamped). Corner pair (x0,x0+1) = one
// aligned 16B entry: j = x0>>1, copy = x0&1.
__global__ __launch_bounds__(256) void pack_kernel(
    const float* __restrict__ inp, uint4* __restrict__ tab)
{
    int t = blockIdx.x * blockDim.x + threadIdx.x;
    if (t >= TOT) return;
    int j = t % WP;
    int y = (t / WP) % HH;
    int b = t / (WP * HH);
    int p0 = 2 * j;
    int p2 = min(2 * j + 2, WW - 1);
    const float* b0 = inp + (((size_t)b * CC + 0) * HH + y) * WW;
    const float* b1 = inp + (((size_t)b * CC + 1) * HH + y) * WW;
    const float* b2 = inp + (((size_t)b * CC + 2) * HH + y) * WW;
    fx2 a0 = *(const fx2*)(b0 + p0);     // p0 even -> 8B aligned
    fx2 a1 = *(const fx2*)(b1 + p0);
    fx2 a2 = *(const fx2*)(b2 + p0);
    float c0 = b0[p2], c1 = b1[p2], c2 = b2[p2];
    uint2 q0 = pack_px(a0.x, a1.x, a2.x);
    uint2 q1 = pack_px(a0.y, a1.y, a2.y);
    uint2 q2 = pack_px(c0, c1, c2);
    tab[t]       = make_uint4(q0.x, q0.y, q1.x, q1.y);   // copy A
    tab[TOT + t] = make_uint4(q1.x, q1.y, q2.x, q2.y);   // copy B
}

__device__ __forceinline__ void unpack_pair(uint4 r,
    float& lo0, float& lo1, float& lo2, float& hi0, float& hi1, float& hi2)
{
    float2 lo01 = __half22float2(*(const __half2*)&r.x);
    float2 hi01 = __half22float2(*(const __half2*)&r.z);
    lo0 = lo01.x; lo1 = lo01.y;
    hi0 = hi01.x; hi1 = hi01.y;
    lo2 = __half2float(*(const __half*)&r.y);
    hi2 = __half2float(*(const __half*)&r.w);
}

// 2 adjacent pixels per thread, 64x2 tile per 1-wave block (64 threads).
// ki fully unrolled with double-buffered stream prefetch: iteration ki
// consumes offsets issued one full kj-loop earlier, so stream latency
// is off the critical path. Gathers stay branch-free (2x16B per tap/px).
__global__ __launch_bounds__(64) void dsepconv_kernel(
    const uint4* __restrict__ tab,
    const float* __restrict__ vert,
    const float* __restrict__ horiz,
    const float* __restrict__ offx,
    const float* __restrict__ offy,
    const float* __restrict__ mask,
    float* __restrict__ out)
{
    int tx = threadIdx.x & 31;
    int ty = threadIdx.x >> 5;
    int xb = blockIdx.x * TX + tx * 2;      // even
    int y  = blockIdx.y * TY + ty;
    int b  = blockIdx.z;
    int planeoff = y * WW + xb;             // 8B aligned

    fx2 v2[FF], h2[FF];
#pragma unroll
    for (int f = 0; f < FF; ++f) {
        v2[f] = nt_load2(vert  + (b * FF + f) * HW + planeoff);
        h2[f] = nt_load2(horiz + (b * FF + f) * HW + planeoff);
    }

    const uint4* tb = tab + (size_t)b * (HH * WP);
    const float* ox_base = offx + (size_t)b * KK * HW + planeoff;
    const float* oy_base = offy + (size_t)b * KK * HW + planeoff;
    const float* m_base  = mask + (size_t)b * KK * HW + planeoff;

    float acc[2][3] = {{0.f,0.f,0.f},{0.f,0.f,0.f}};
    const float fy = (float)y;

    // depth-2 stream pipeline (all indices compile-time after unroll)
    fx2 oxb[2][FF], oyb[2][FF], mb[2][FF];
#pragma unroll
    for (int kj = 0; kj < FF; ++kj) {
        oxb[0][kj] = nt_load2(ox_base + kj * HW);
        oyb[0][kj] = nt_load2(oy_base + kj * HW);
        mb[0][kj]  = nt_load2(m_base  + kj * HW);
    }

#pragma unroll
    for (int ki = 0; ki < FF; ++ki) {
        const int cur = ki & 1, nxt = cur ^ 1;
        if (ki + 1 < FF) {               // issue next row's streams first
#pragma unroll
            for (int kj = 0; kj < FF; ++kj) {
                oxb[nxt][kj] = nt_load2(ox_base + ((ki+1) * FF + kj) * HW);
                oyb[nxt][kj] = nt_load2(oy_base + ((ki+1) * FF + kj) * HW);
                mb[nxt][kj]  = nt_load2(m_base  + ((ki+1) * FF + kj) * HW);
            }
        }
        const float dy = fy + (float)(ki - 2);
#pragma unroll
        for (int kj = 0; kj < FF; ++kj) {
            fx2 ox2 = oxb[cur][kj];
            fx2 oy2 = oyb[cur][kj];
            fx2 m2  = mb[cur][kj];
#pragma unroll
            for (int p = 0; p < 2; ++p) {
                float wt = v2[ki][p] * h2[kj][p] * m2[p];
                float py = oy2[p] + dy;
                float px = ox2[p] + (float)(xb + p + kj - 2);
                py = fminf(fmaxf(py, 0.f), (float)(HH - 1));
                px = fminf(fmaxf(px, 0.f), (float)(WW - 1));
                float y0f = floorf(py);
                float x0f = floorf(px);
                float wy = py - y0f;
                float wx = px - x0f;
                int y0 = (int)y0f;
                int x0 = (int)x0f;
                int y1 = min(y0 + 1, HH - 1);

                int j    = x0 >> 1;
                const uint4* tbs = tb + ((x0 & 1) ? TOT : 0);
                uint4 r0 = tbs[y0 * WP + j];
                uint4 r1 = tbs[y1 * WP + j];

                float a00,a01,a02,b00,b01,b02;
                float a10,a11,a12,b10,b11,b12;
                unpack_pair(r0, a00,a01,a02, b00,b01,b02);
                unpack_pair(r1, a10,a11,a12, b10,b11,b12);

                float w00 = (1.f - wy) * (1.f - wx);
                float w01 = (1.f - wy) * wx;
                float w10 = wy * (1.f - wx);
                float w11 = wy * wx;

                acc[p][0] += wt * (a00*w00 + b00*w01 + a10*w10 + b10*w11);
                acc[p][1] += wt * (a01*w00 + b01*w01 + a11*w10 + b11*w11);
                acc[p][2] += wt * (a02*w00 + b02*w01 + a12*w10 + b12*w11);
            }
        }
    }

#pragma unroll
    for (int c = 0; c < CC; ++c) {
        fx2 o; o.x = acc[0][c]; o.y = acc[1][c];
        *(fx2*)(out + ((size_t)b * CC + c) * HW + planeoff) = o;
    }
}

extern "C" void kernel_launch(void* const* d_in, const int* in_sizes, int n_in,
                              void* d_out, int out_size, void* d_ws, size_t ws_size,
                              hipStream_t stream) {
    const float* inp   = (const float*)d_in[0];
    const float* vert  = (const float*)d_in[1];
    const float* horiz = (const float*)d_in[2];
    const float* offx  = (const float*)d_in[3];
    const float* offy  = (const float*)d_in[4];
    const float* mask  = (const float*)d_in[5];
    float* out = (float*)d_out;
    uint4* tab = (uint4*)d_ws;   // 2 x 4.72 MB

    {
        pack_kernel<<<(TOT + 255) / 256, 256, 0, stream>>>(inp, tab);
    }
    {
        dim3 grid(WW / TX, HH / TY, BB);   // 6 x 192 x 4, 1 wave per block
        dsepconv_kernel<<<grid, 64, 0, stream>>>(
            tab, vert, horiz, offx, offy, mask, out);
    }
}

// Round 4
// 250.253 us; speedup vs baseline: 1.0775x; 1.0775x over previous
//
#include <hip/hip_runtime.h>
#include <hip/hip_fp16.h>

#define BB 4
#define CC 3
#define HH 384
#define WW 384
#define FF 5
#define KK 25            // FF*FF
#define HW (HH*WW)

#define TX 64            // tile width (pixels) — 32 lanes x 2 px
#define TY 8             // tile height
#define MX 10            // x margin: covers |offx| <= 7 (escape P ~1e-12/sample)
#define MY 9             // y margin: covers |offy| <= 7
#define RH (TY + 2*MY + 2)     // 28 staged rows  [Y-9 .. Y+18]
#define RWS (TX + 2*MX + 2)    // 86 staged cols  [X-10 .. X+75]
#define SMN (RH*RWS)           // 2408 staged pixels
// LDS layout: [row][plane][RWS] dwords. plane0 = h(c0)|h(c1), plane1 = h(c2).
// Lane stride on tap reads = 8B over 4B words -> 2-way bank alias (free).

typedef float fx2 __attribute__((ext_vector_type(2)));

__device__ __forceinline__ fx2 nt_load2(const float* p) {
    return __builtin_nontemporal_load((const fx2*)p);
}

// pack one pixel (3 fp32 channels) -> 8B: x = h(c0)|h(c1)<<16, y = h(c2)
__device__ __forceinline__ uint2 pack_px(float c0, float c1, float c2) {
    __half2 h01 = __floats2half2_rn(c0, c1);
    uint2 r;
    r.x = *(const unsigned int*)&h01;
    r.y = (unsigned int)__half_as_ushort(__float2half_rn(c2));
    return r;
}

// Single packed fp16 pixel table: tab[b*HW + y*WW + x] = packed pixel (8B).
__global__ __launch_bounds__(256) void pack_kernel(
    const float* __restrict__ inp, uint2* __restrict__ tab)
{
    int t = blockIdx.x * blockDim.x + threadIdx.x;
    if (t >= BB * HW) return;
    int b = t / HW;
    const float* p0 = inp + (size_t)t + (size_t)b * 2 * HW;  // c0 plane
    tab[t] = pack_px(p0[0], p0[HW], p0[2 * HW]);
}

// Fused kernel: stage 28x86 fp16 pixel region in LDS (plane-split), then
// 2 px/thread deformable-sepconv with all bilinear taps served from LDS.
// Staging clamp realizes the reference's border clamping, so interior tap
// reads need no edge selects. Out-of-margin offsets (|off|>7, ~never) are
// handled exactly by a wave-uniform fp32 global fallback.
__global__ __launch_bounds__(256) void dsepconv_kernel(
    const uint2* __restrict__ tab,
    const float* __restrict__ inp,
    const float* __restrict__ vert,
    const float* __restrict__ horiz,
    const float* __restrict__ offx,
    const float* __restrict__ offy,
    const float* __restrict__ mask,
    float* __restrict__ out)
{
    __shared__ unsigned int lds[RH * 2 * RWS];   // 19264 B

    int tx = threadIdx.x & 31;
    int ty = threadIdx.x >> 5;
    int X  = blockIdx.x * TX;
    int Y  = blockIdx.y * TY;
    int xb = X + tx * 2;                 // even
    int y  = Y + ty;
    int b  = blockIdx.z;
    int ylo = Y - MY, xlo = X - MX;
    int planeoff = y * WW + xb;          // 8B aligned

    // ---- stage packed pixels (coalesced 8B loads from the fp16 table) ----
    const uint2* tb = tab + (size_t)b * HW;
    for (int p = threadIdx.x; p < SMN; p += 256) {
        int r = p / RWS;                 // constant divisor -> magic mul
        int c = p - r * RWS;
        int gy = min(max(ylo + r, 0), HH - 1);
        int gx = min(max(xlo + c, 0), WW - 1);
        uint2 q = tb[gy * WW + gx];
        lds[(r * 2) * RWS + c]     = q.x;    // plane0: c0|c1
        lds[(r * 2 + 1) * RWS + c] = q.y;    // plane1: c2
    }
    __syncthreads();

    fx2 v2[FF], h2[FF];
#pragma unroll
    for (int f = 0; f < FF; ++f) {
        v2[f] = nt_load2(vert  + (b * FF + f) * HW + planeoff);
        h2[f] = nt_load2(horiz + (b * FF + f) * HW + planeoff);
    }

    const float* c0p = inp + ((size_t)b * CC + 0) * HW;
    const float* c1p = inp + ((size_t)b * CC + 1) * HW;
    const float* c2p = inp + ((size_t)b * CC + 2) * HW;

    float acc[2][3] = {{0.f,0.f,0.f},{0.f,0.f,0.f}};
    const float fy = (float)y;

    for (int ki = 0; ki < FF; ++ki) {
        float dy = fy + (float)(ki - 2);
        const float* ox_p = offx + (size_t)(b * KK + ki * FF) * HW + planeoff;
        const float* oy_p = offy + (size_t)(b * KK + ki * FF) * HW + planeoff;
        const float* m_p  = mask + (size_t)(b * KK + ki * FF) * HW + planeoff;
#pragma unroll
        for (int kj = 0; kj < FF; ++kj) {
            fx2 ox2 = nt_load2(ox_p + kj * HW);
            fx2 oy2 = nt_load2(oy_p + kj * HW);
            fx2 m2  = nt_load2(m_p  + kj * HW);
#pragma unroll
            for (int p = 0; p < 2; ++p) {
                float wt = v2[ki][p] * h2[kj][p] * m2[p];
                float py = oy2[p] + dy;
                float px = ox2[p] + (float)(xb + p + kj - 2);
                py = fminf(fmaxf(py, 0.f), (float)(HH - 1));
                px = fminf(fmaxf(px, 0.f), (float)(WW - 1));
                float y0f = floorf(py);
                float x0f = floorf(px);
                float wy = py - y0f;
                float wx = px - x0f;
                int y0 = (int)y0f;
                int x0 = (int)x0f;

                int y0r = y0 - ylo;
                int x0r = x0 - xlo;
                bool ok = ((unsigned)y0r <= (unsigned)(RH - 2)) &
                          ((unsigned)x0r <= (unsigned)(RWS - 2));
                int yc = min(max(y0r, 0), RH - 2);
                int xc = min(max(x0r, 0), RWS - 2);
                int a0 = (yc * 2) * RWS + xc;

                // unconditional LDS reads (clamped addr; garbage iff !ok)
                unsigned p00 = lds[a0],           p01 = lds[a0 + 1];
                unsigned q00 = lds[a0 + RWS],     q01 = lds[a0 + RWS + 1];
                unsigned p10 = lds[a0 + 2*RWS],   p11 = lds[a0 + 2*RWS + 1];
                unsigned q10 = lds[a0 + 3*RWS],   q11 = lds[a0 + 3*RWS + 1];

                float2 f00 = __half22float2(*(const __half2*)&p00);
                float2 f01 = __half22float2(*(const __half2*)&p01);
                float2 f10 = __half22float2(*(const __half2*)&p10);
                float2 f11 = __half22float2(*(const __half2*)&p11);
                float s00c0 = f00.x, s00c1 = f00.y;
                float s01c0 = f01.x, s01c1 = f01.y;
                float s10c0 = f10.x, s10c1 = f10.y;
                float s11c0 = f11.x, s11c1 = f11.y;
                float s00c2 = __half2float(*(const __half*)&q00);
                float s01c2 = __half2float(*(const __half*)&q01);
                float s10c2 = __half2float(*(const __half*)&q10);
                float s11c2 = __half2float(*(const __half*)&q11);

                // correctness net: wave-uniform, statistically never taken
                if (__builtin_expect(!__all((int)ok), 0)) {
                    if (!ok) {
                        int x1 = min(x0 + 1, WW - 1);
                        int y1g = min(y0 + 1, HH - 1);
                        int o00 = y0 * WW + x0,  o01 = y0 * WW + x1;
                        int o10 = y1g * WW + x0, o11 = y1g * WW + x1;
                        s00c0 = c0p[o00]; s00c1 = c1p[o00]; s00c2 = c2p[o00];
                        s01c0 = c0p[o01]; s01c1 = c1p[o01]; s01c2 = c2p[o01];
                        s10c0 = c0p[o10]; s10c1 = c1p[o10]; s10c2 = c2p[o10];
                        s11c0 = c0p[o11]; s11c1 = c1p[o11]; s11c2 = c2p[o11];
                    }
                }

                float w00 = (1.f - wy) * (1.f - wx);
                float w01 = (1.f - wy) * wx;
                float w10 = wy * (1.f - wx);
                float w11 = wy * wx;

                acc[p][0] += wt * (s00c0*w00 + s01c0*w01 + s10c0*w10 + s11c0*w11);
                acc[p][1] += wt * (s00c1*w00 + s01c1*w01 + s10c1*w10 + s11c1*w11);
                acc[p][2] += wt * (s00c2*w00 + s01c2*w01 + s10c2*w10 + s11c2*w11);
            }
        }
    }

#pragma unroll
    for (int c = 0; c < CC; ++c) {
        fx2 o; o.x = acc[0][c]; o.y = acc[1][c];
        *(fx2*)(out + ((size_t)b * CC + c) * HW + planeoff) = o;
    }
}

extern "C" void kernel_launch(void* const* d_in, const int* in_sizes, int n_in,
                              void* d_out, int out_size, void* d_ws, size_t ws_size,
                              hipStream_t stream) {
    const float* inp   = (const float*)d_in[0];
    const float* vert  = (const float*)d_in[1];
    const float* horiz = (const float*)d_in[2];
    const float* offx  = (const float*)d_in[3];
    const float* offy  = (const float*)d_in[4];
    const float* mask  = (const float*)d_in[5];
    float* out = (float*)d_out;
    uint2* tab = (uint2*)d_ws;   // 4.72 MB packed fp16 pixel table

    {
        pack_kernel<<<(BB * HW + 255) / 256, 256, 0, stream>>>(inp, tab);
    }
    {
        dim3 grid(WW / TX, HH / TY, BB);   // 6 x 48 x 4
        dsepconv_kernel<<<grid, 256, 0, stream>>>(
            tab, inp, vert, horiz, offx, offy, mask, out);
    }
}